// Round 8
// baseline (116.483 us; speedup 1.0000x reference)
//
#include <hip/hip_runtime.h>

// Problem constants
#define B_DIM   4096
#define C_DIM   128
#define P_IDS   256          // B/K_INST
#define INV_TEMP 20.0f       // 1/0.05
#define EPS 1e-6f

#define A_CHUNKS 65536       // 4096*128/8  (bf16x8 chunks)
#define B_CHUNKS 524288      // 32768*128/8
#define ALL_CHUNKS (A_CHUNKS + B_CHUNKS)

typedef unsigned short u16;
typedef __attribute__((ext_vector_type(8))) short bf16x8;
typedef __attribute__((ext_vector_type(16))) float f32x16;

__device__ __forceinline__ u16 f2bf(float x) {
    union { float f; unsigned u; } v; v.f = x;
    unsigned r = v.u + 0x7fffu + ((v.u >> 16) & 1u);   // RTN-even
    return (u16)(r >> 16);
}

// ---------------- kernel 1: fp32 -> bf16 fragment-tiled (32x32x16 layout) ----------------
// Chunk c (16B = 8 bf16): grp=c2>>9, kseg=(c2>>6)&7, lane=c2&63 ->
// holds SRC[grp*32 + (lane&31)][kseg*16 + (lane>>5)*8 .. +8]
// (mfma_32x32x16 operand layout: row=lane&31, k=(lane>>5)*8).
// Chunks 0..65535 = feats (A), 65536.. = feats_s (B). Boundary block-aligned.
__global__ __launch_bounds__(256) void convert_bf16(const float* __restrict__ feats,
                                                    const float* __restrict__ feats_s,
                                                    u16* __restrict__ T) {
    const int c = blockIdx.x * 256 + threadIdx.x;
    const float* base; int c2;
    if (c < A_CHUNKS) { base = feats;   c2 = c; }
    else              { base = feats_s; c2 = c - A_CHUNKS; }
    const int grp = c2 >> 9, kseg = (c2 >> 6) & 7, lane = c2 & 63;
    const float* src = base + (size_t)(grp * 32 + (lane & 31)) * C_DIM
                            + kseg * 16 + (lane >> 5) * 8;
    float4 u0 = *(const float4*)src;
    float4 u1 = *(const float4*)(src + 4);
    bf16x8 o;
    o[0] = (short)f2bf(u0.x); o[1] = (short)f2bf(u0.y);
    o[2] = (short)f2bf(u0.z); o[3] = (short)f2bf(u0.w);
    o[4] = (short)f2bf(u1.x); o[5] = (short)f2bf(u1.y);
    o[6] = (short)f2bf(u1.z); o[7] = (short)f2bf(u1.w);
    *(bf16x8*)(T + (size_t)c * 8) = o;
}

// ---------------- kernel 2: zero-LDS streaming sim, 32x32x16 MFMA ----------------
// R15 vs R14 (111.6 us): cross-round accounting shows phase1 ~40-42 us in
// R11/R12/R14 despite three different B-handling structures -> the limiter is
// the 16x16x32 structure itself (32 MFMA issue slots + 2 epilogue folds per
// 32 rows), not B remat.
//  * mfma_f32_32x32x16_bf16: 16 MFMAs per 32 rows (2x FLOP each, +15% rate,
//    floor 16.6 -> 14.4 us), ONE 31-op fold + ONE shfl per 32 rows, 128B
//    stores (lanes 0-31).
//  * Half-K software pipeline: aA/aB hold 4 ksegs each -> reg peak ~152 ->
//    __launch_bounds__(256,3): 3 waves/SIMD (up from 2).
//  * Opacity barrier on b[2][8] retained (R14): remat impossible.
// Retained: zero LDS, zero barriers, [wn][p][row] pmax, pre-tiled bf16 A+B.
__global__ __launch_bounds__(256, 3) void phase1(const u16*  __restrict__ T,   // frag-tiled bf16: A then B
                                                 float* __restrict__ pmax,     // [2][256][4096]
                                                 float* __restrict__ pmin)     // [2][4096]
{
    const int tid  = threadIdx.x;
    const int lane = tid & 63;
    const int wave = tid >> 6;
    const int wm   = wave >> 1;       // row half of block's 1024 rows (512 each)
    const int wn   = wave & 1;        // col half (64 of 128 support cols)
    const int p    = blockIdx.x;      // identity 0..255
    const int h    = blockIdx.y;      // row quarter: rows h*1024..+1023

    // ---- B fragments: 16 one-time global loads -> 64 VGPRs, then OPAQUE ----
    // b[t][k] holds B[(p*4+wn*2+t)*32 + (lane&31)][k*16 + (lane>>5)*8 .. +8]
    const u16* bbase = T + (size_t)A_CHUNKS * 8
                         + ((size_t)(p * 4 + wn * 2) * 512 + lane) * 8;
    bf16x8 b[2][8];
#pragma unroll
    for (int t = 0; t < 2; ++t)
#pragma unroll
        for (int k = 0; k < 8; ++k)
            b[t][k] = *(const bf16x8*)(bbase + t * 4096 + k * 512);
#pragma unroll
    for (int t = 0; t < 2; ++t)
#pragma unroll
        for (int k = 0; k < 8; ++k)
            asm volatile("" : "+v"(b[t][k]));

    // ---- A stream: 16 steps of 32 rows ----
    const int G0 = h * 32 + wm * 16;                        // 32-row group base
    const u16* abase = T + ((size_t)G0 * 512 + lane) * 8;   // +s*4096, +kseg*512 (u16)

    // pmax [wn][p][row]: wave owns rows h*1024 + wm*512 .. +511 at (wn,p)
    float* const pq = pmax + ((size_t)wn * P_IDS + p) * B_DIM + h * 1024 + wm * 512;
    const bool dhit = (h == (p >> 6)) && (wm == ((p >> 5) & 1));
    const int  ssel = (p >> 1) & 15;  // step holding anchor rows p*16..+16
    const int  hsel = p & 1;          // which 16-lane half of the 32-row step

#define LOADH(dst, ss, hf) do { const u16* ap = abase + (size_t)(ss) * 4096 + (hf) * 2048; \
        dst[0] = *(const bf16x8*)ap;          dst[1] = *(const bf16x8*)(ap + 512);  \
        dst[2] = *(const bf16x8*)(ap + 1024); dst[3] = *(const bf16x8*)(ap + 1536); } while (0)

    bf16x8 aA[4], aB[4];
    LOADH(aA, 0, 0);
#pragma unroll 1
    for (int s = 0; s < 16; ++s) {
        LOADH(aB, s, 1);              // ksegs 4-7 of this step (overlaps first MFMAs)
        f32x16 acc0 = {}, acc1 = {};  // [t=0], [t=1]: two 32-col tiles
        // D[n=anchor row (lane&31)][m=support col]: operands swapped
#pragma unroll
        for (int k = 0; k < 4; ++k) {
            acc0 = __builtin_amdgcn_mfma_f32_32x32x16_bf16(b[0][k], aA[k], acc0, 0, 0, 0);
            acc1 = __builtin_amdgcn_mfma_f32_32x32x16_bf16(b[1][k], aA[k], acc1, 0, 0, 0);
        }
        if (s < 15) LOADH(aA, s + 1, 0);   // prefetch next step's ksegs 0-3
#pragma unroll
        for (int k = 0; k < 4; ++k) {
            acc0 = __builtin_amdgcn_mfma_f32_32x32x16_bf16(b[0][4 + k], aB[k], acc0, 0, 0, 0);
            acc1 = __builtin_amdgcn_mfma_f32_32x32x16_bf16(b[1][4 + k], aB[k], acc1, 0, 0, 0);
        }

        // ---- epilogue: per-anchor-row max over wave's 64 support cols ----
        // lane l and l+32 hold the same anchor row (lane&31), different col
        // subsets -> fold 32 regs (31 fmax, low-pressure 8-temp form) + 1 shfl.
        float m[8];
#pragma unroll
        for (int i = 0; i < 8; ++i)
            m[i] = fmaxf(fmaxf(acc0[i], acc0[i + 8]), fmaxf(acc1[i], acc1[i + 8]));
        m[0] = fmaxf(m[0], m[4]); m[1] = fmaxf(m[1], m[5]);
        m[2] = fmaxf(m[2], m[6]); m[3] = fmaxf(m[3], m[7]);
        m[0] = fmaxf(m[0], m[2]); m[1] = fmaxf(m[1], m[3]);
        float mx = fmaxf(m[0], m[1]);
        mx = fmaxf(mx, __shfl_xor(mx, 32, 64));
        if (lane < 32) pq[s * 32 + lane] = mx;

        // ---- diagonal min (anchor identity's own 16 rows x this wn's 64 cols) ----
        if (dhit && s == ssel) {
            float n[8];
#pragma unroll
            for (int i = 0; i < 8; ++i)
                n[i] = fminf(fminf(acc0[i], acc0[i + 8]), fminf(acc1[i], acc1[i + 8]));
            n[0] = fminf(n[0], n[4]); n[1] = fminf(n[1], n[5]);
            n[2] = fminf(n[2], n[6]); n[3] = fminf(n[3], n[7]);
            n[0] = fminf(n[0], n[2]); n[1] = fminf(n[1], n[3]);
            float mn = fminf(n[0], n[1]);
            mn = fminf(mn, __shfl_xor(mn, 32, 64));
            if (lane < 32 && ((lane >> 4) & 1) == hsel)
                pmin[wn * B_DIM + p * 16 + (lane & 15)] = mn;
        }
    }
#undef LOADH
}

// ---------------- kernel 3: per-row loss + mean (stripe-transposed reads) ----------------
// 64 blocks x 256 thr. Block owns a 64-row stripe; lane = row, wave owns a
// 64-wide p-range. Every pmax load is a coalesced 256B line (L2-resident).
__global__ __launch_bounds__(256) void phase2(const float* __restrict__ pmax,  // [2][256][4096]
                                              const float* __restrict__ pmin,  // [2][4096]
                                              const int* __restrict__ labels,
                                              float* __restrict__ out) {
    const int tid  = threadIdx.x;
    const int lane = tid & 63;
    const int wave = tid >> 6;
    const int row  = blockIdx.x * 64 + lane;
    const int pid  = labels[row];
    const float* q0 = pmax + (size_t)(wave * 64) * B_DIM + row;   // p = wave*64+j
    const float* q1 = q0 + (size_t)P_IDS * B_DIM;
    float s = 0.f;
#pragma unroll 8
    for (int j = 0; j < 64; ++j) {
        const int p  = wave * 64 + j;
        const float v = fmaxf(q0[(size_t)j * B_DIM], q1[(size_t)j * B_DIM]);
        s += (p == pid) ? 0.f : __expf(v * INV_TEMP);
    }
    __shared__ float part[4][64];
    part[wave][lane] = s;
    __syncthreads();
    if (wave == 0) {
        const float neg = part[0][lane] + part[1][lane] + part[2][lane] + part[3][lane];
        const float mn  = fminf(pmin[row], pmin[B_DIM + row]);
        const float pos = __expf(mn * INV_TEMP);
        float loss = -__logf(pos / (pos + neg + EPS) + EPS);
        loss += __shfl_xor(loss, 1, 64);
        loss += __shfl_xor(loss, 2, 64);
        loss += __shfl_xor(loss, 4, 64);
        loss += __shfl_xor(loss, 8, 64);
        loss += __shfl_xor(loss, 16, 64);
        loss += __shfl_xor(loss, 32, 64);
        if (lane == 0) atomicAdd(out, loss * (1.0f / (float)B_DIM));
    }
}

extern "C" void kernel_launch(void* const* d_in, const int* in_sizes, int n_in,
                              void* d_out, int out_size, void* d_ws, size_t ws_size,
                              hipStream_t stream) {
    const float* feats   = (const float*)d_in[0];   // [4096,128]
    const float* feats_s = (const float*)d_in[1];   // [4096,8,128] fp32
    const int*   labels  = (const int*)d_in[2];     // [4096]
    float* out = (float*)d_out;

    // workspace: T = frag-tiled bf16 A(1 MB)+B(8 MB) | pmax (8 MB) | pmin (32 KB)
    u16* T = (u16*)d_ws;
    float* pmax = (float*)((char*)d_ws + (16u << 20));
    float* pmin = pmax + (size_t)2 * P_IDS * B_DIM;

    hipMemsetAsync(d_out, 0, sizeof(float), stream);
    convert_bf16<<<ALL_CHUNKS / 256, 256, 0, stream>>>(feats, feats_s, T);
    dim3 g1(P_IDS, 4);
    phase1<<<g1, 256, 0, stream>>>(T, pmax, pmin);
    phase2<<<B_DIM / 64, 256, 0, stream>>>(pmax, pmin, labels, out);
}

// Round 9
// 112.091 us; speedup vs baseline: 1.0392x; 1.0392x over previous
//
#include <hip/hip_runtime.h>

// Problem constants
#define B_DIM   4096
#define C_DIM   128
#define P_IDS   256          // B/K_INST
#define INV_TEMP 20.0f       // 1/0.05
#define EPS 1e-6f

#define A_CHUNKS 65536       // 4096*128/8  (bf16x8 chunks)
#define B_CHUNKS 524288      // 32768*128/8
#define ALL_CHUNKS (A_CHUNKS + B_CHUNKS)

typedef unsigned short u16;
typedef __attribute__((ext_vector_type(8))) short bf16x8;
typedef __attribute__((ext_vector_type(4))) float f32x4;

__device__ __forceinline__ u16 f2bf(float x) {
    union { float f; unsigned u; } v; v.f = x;
    unsigned r = v.u + 0x7fffu + ((v.u >> 16) & 1u);   // RTN-even
    return (u16)(r >> 16);
}

// ---------------- kernel 1: fp32 -> bf16 fragment-tiled A and B ----------------
// Chunk c (16B = 8 bf16): grow=c2>>8, kk=(c2>>6)&3, lane=c2&63, g=lane>>4,
// r=lane&15 -> holds SRC[grow*16 + r][kk*32 + g*8 .. +8].
// Chunks 0..65535 = feats (A), 65536.. = feats_s (B). Boundary block-aligned.
__global__ __launch_bounds__(256) void convert_bf16(const float* __restrict__ feats,
                                                    const float* __restrict__ feats_s,
                                                    u16* __restrict__ T) {
    const int c = blockIdx.x * 256 + threadIdx.x;
    const float* base; int c2;
    if (c < A_CHUNKS) { base = feats;   c2 = c; }
    else              { base = feats_s; c2 = c - A_CHUNKS; }
    const int grow = c2 >> 8, kk = (c2 >> 6) & 3, lane = c2 & 63;
    const int g = lane >> 4, r = lane & 15;
    const float* src = base + (size_t)(grow * 16 + r) * C_DIM + kk * 32 + g * 8;
    float4 u0 = *(const float4*)src;
    float4 u1 = *(const float4*)(src + 4);
    bf16x8 o;
    o[0] = (short)f2bf(u0.x); o[1] = (short)f2bf(u0.y);
    o[2] = (short)f2bf(u0.z); o[3] = (short)f2bf(u0.w);
    o[4] = (short)f2bf(u1.x); o[5] = (short)f2bf(u1.y);
    o[6] = (short)f2bf(u1.z); o[7] = (short)f2bf(u1.w);
    *(bf16x8*)(T + (size_t)c * 8) = o;
}

// ---------------- kernel 2: zero-LDS streaming sim + max/min ----------------
// R16 vs R15 (116.5, regression -> reverted to R12 base, best at 109.6):
//  * Model update: R14 proved more TLP (2->3 waves/SIMD) changes nothing;
//    phase1 (~30 us vs 16.6 MFMA-floor) is per-wave LATENCY-bound: depth-1
//    prefetch issues the A-fragment load only ~155 CU-cyc of MFMA before its
//    use, but L2 latency is ~200+ cyc -> every wave stalls every step, and
//    homogeneous waves all stall together.
//  * Fix (ILP, not TLP): depth-2 prefetch. Four named buffers F0-F3,
//    unroll-4 body, every load issued 2 STEPs (~310 cyc) ahead of use.
//    All indexing compile-time (dynamic-index -> scratch, R1 lesson).
//  * VGPR: b(64, opacity-pinned) + F(64) + acc(16) + addr ~15 = ~160 <= 168
//    -> __launch_bounds__(256,3) holds, no spill.
// Retained: zero LDS / zero barriers, pre-tiled bf16 A+B (remat trap closed:
// opacity barrier on b), swapped MFMA operands, [wn][p][row] pmax
// (exclusive 64B-line stores), balanced-tree epilogue fold.
__global__ __launch_bounds__(256, 3) void phase1(const u16*  __restrict__ T,   // frag-tiled bf16: A then B
                                                 float* __restrict__ pmax,     // [2][256][4096]
                                                 float* __restrict__ pmin)     // [2][4096]
{
    const int tid  = threadIdx.x;
    const int lane = tid & 63;
    const int wave = tid >> 6;
    const int wm   = wave >> 1;       // row half of block's 1024 rows
    const int wn   = wave & 1;        // col half (64 of 128 support cols)
    const int p    = blockIdx.x;      // identity 0..255
    const int h    = blockIdx.y;      // row quarter: rows h*1024..+1023

    // ---- B fragments: 16 one-time global loads -> 64 VGPRs, then OPAQUE ----
    const u16* bbase = T + (size_t)A_CHUNKS * 8
                         + ((size_t)(p * 8 + wn * 4) * 256 + lane) * 8;
    bf16x8 b[4][4];                   // [ni][kk]
#pragma unroll
    for (int ni = 0; ni < 4; ++ni)
#pragma unroll
        for (int kk = 0; kk < 4; ++kk)
            b[ni][kk] = *(const bf16x8*)(bbase + ni * 2048 + kk * 512);
    // Opacity barrier: origin now unknowable -> rematerialization impossible,
    // b stays pinned in registers for the whole loop.
#pragma unroll
    for (int ni = 0; ni < 4; ++ni)
#pragma unroll
        for (int kk = 0; kk < 4; ++kk)
            asm volatile("" : "+v"(b[ni][kk]));

    // ---- A stream addressing: 32 steps of 16 rows ----
    const int grow0 = h * 64 + wm * 32;                      // global row-group base
    const u16* abase = T + ((size_t)grow0 * 256 + lane) * 8; // +s*2048, +kk*512 (u16)

    // pmax [wn][p][row]: this wave owns rows h*1024 + wm*512 .. +511 at (wn,p)
    float* const pq = pmax + ((size_t)wn * P_IDS + p) * B_DIM + h * 1024 + wm * 512;
    const bool dhit = (h == (p >> 6)) && (wm == ((p >> 5) & 1));
    const int  ssel = p & 31;

#define LOADA(dst, ss) do { const u16* ap = abase + (size_t)(ss) * 2048;         \
        dst[0] = *(const bf16x8*)ap;         dst[1] = *(const bf16x8*)(ap + 512); \
        dst[2] = *(const bf16x8*)(ap + 1024); dst[3] = *(const bf16x8*)(ap + 1536); } while (0)

    // D[n][m] per lane (operands swapped): col(lane&15)=A-row, row(g*4+rr)=B-col
#define STEP(areg, ss) do {                                                       \
        f32x4 acc[4] = {};                                                        \
        _Pragma("unroll")                                                         \
        for (int kk = 0; kk < 4; ++kk) {                                          \
            _Pragma("unroll")                                                     \
            for (int ni = 0; ni < 4; ++ni)                                        \
                acc[ni] = __builtin_amdgcn_mfma_f32_16x16x32_bf16(                \
                    b[ni][kk], areg[kk], acc[ni], 0, 0, 0);                       \
        }                                                                         \
        float t0 = fmaxf(fmaxf(acc[0][0], acc[0][1]), fmaxf(acc[0][2], acc[0][3]));\
        float t1 = fmaxf(fmaxf(acc[1][0], acc[1][1]), fmaxf(acc[1][2], acc[1][3]));\
        float t2 = fmaxf(fmaxf(acc[2][0], acc[2][1]), fmaxf(acc[2][2], acc[2][3]));\
        float t3 = fmaxf(fmaxf(acc[3][0], acc[3][1]), fmaxf(acc[3][2], acc[3][3]));\
        float mx = fmaxf(fmaxf(t0, t1), fmaxf(t2, t3));                           \
        mx = fmaxf(mx, __shfl_xor(mx, 16, 64));                                   \
        mx = fmaxf(mx, __shfl_xor(mx, 32, 64));                                   \
        if (lane < 16) pq[(ss) * 16 + lane] = mx;                                 \
        if (dhit && (ss) == ssel) {                                               \
            float n0 = fminf(fminf(acc[0][0], acc[0][1]), fminf(acc[0][2], acc[0][3]));\
            float n1 = fminf(fminf(acc[1][0], acc[1][1]), fminf(acc[1][2], acc[1][3]));\
            float n2 = fminf(fminf(acc[2][0], acc[2][1]), fminf(acc[2][2], acc[2][3]));\
            float n3 = fminf(fminf(acc[3][0], acc[3][1]), fminf(acc[3][2], acc[3][3]));\
            float mn = fminf(fminf(n0, n1), fminf(n2, n3));                       \
            mn = fminf(mn, __shfl_xor(mn, 16, 64));                               \
            mn = fminf(mn, __shfl_xor(mn, 32, 64));                               \
            if (lane < 16) pmin[wn * B_DIM + p * 16 + lane] = mn;                 \
        }                                                                         \
    } while (0)

    // ---- depth-2 software pipeline: 4 rolling buffers, unroll-4 body ----
    bf16x8 F0[4], F1[4], F2[4], F3[4];
    LOADA(F0, 0);
    LOADA(F1, 1);
#pragma unroll 1
    for (int s = 0; s < 32; s += 4) {
        LOADA(F2, s + 2);                  // 2 steps ahead of its STEP
        STEP(F0, s);
        LOADA(F3, s + 3);
        STEP(F1, s + 1);
        if (s + 4 < 32) LOADA(F0, s + 4);
        STEP(F2, s + 2);
        if (s + 5 < 32) LOADA(F1, s + 5);
        STEP(F3, s + 3);
    }
#undef LOADA
#undef STEP
}

// ---------------- kernel 3: per-row loss + mean (stripe-transposed reads) ----------------
// 64 blocks x 256 thr. Block owns a 64-row stripe; lane = row, wave owns a
// 64-wide p-range. Every pmax load is a coalesced 256B line (L2-resident).
__global__ __launch_bounds__(256) void phase2(const float* __restrict__ pmax,  // [2][256][4096]
                                              const float* __restrict__ pmin,  // [2][4096]
                                              const int* __restrict__ labels,
                                              float* __restrict__ out) {
    const int tid  = threadIdx.x;
    const int lane = tid & 63;
    const int wave = tid >> 6;
    const int row  = blockIdx.x * 64 + lane;
    const int pid  = labels[row];
    const float* q0 = pmax + (size_t)(wave * 64) * B_DIM + row;   // p = wave*64+j
    const float* q1 = q0 + (size_t)P_IDS * B_DIM;
    float s = 0.f;
#pragma unroll 8
    for (int j = 0; j < 64; ++j) {
        const int p  = wave * 64 + j;
        const float v = fmaxf(q0[(size_t)j * B_DIM], q1[(size_t)j * B_DIM]);
        s += (p == pid) ? 0.f : __expf(v * INV_TEMP);
    }
    __shared__ float part[4][64];
    part[wave][lane] = s;
    __syncthreads();
    if (wave == 0) {
        const float neg = part[0][lane] + part[1][lane] + part[2][lane] + part[3][lane];
        const float mn  = fminf(pmin[row], pmin[B_DIM + row]);
        const float pos = __expf(mn * INV_TEMP);
        float loss = -__logf(pos / (pos + neg + EPS) + EPS);
        loss += __shfl_xor(loss, 1, 64);
        loss += __shfl_xor(loss, 2, 64);
        loss += __shfl_xor(loss, 4, 64);
        loss += __shfl_xor(loss, 8, 64);
        loss += __shfl_xor(loss, 16, 64);
        loss += __shfl_xor(loss, 32, 64);
        if (lane == 0) atomicAdd(out, loss * (1.0f / (float)B_DIM));
    }
}

extern "C" void kernel_launch(void* const* d_in, const int* in_sizes, int n_in,
                              void* d_out, int out_size, void* d_ws, size_t ws_size,
                              hipStream_t stream) {
    const float* feats   = (const float*)d_in[0];   // [4096,128]
    const float* feats_s = (const float*)d_in[1];   // [4096,8,128] fp32
    const int*   labels  = (const int*)d_in[2];     // [4096]
    float* out = (float*)d_out;

    // workspace: T = frag-tiled bf16 A(1 MB)+B(8 MB) | pmax (8 MB) | pmin (32 KB)
    u16* T = (u16*)d_ws;
    float* pmax = (float*)((char*)d_ws + (16u << 20));
    float* pmin = pmax + (size_t)2 * P_IDS * B_DIM;

    hipMemsetAsync(d_out, 0, sizeof(float), stream);
    convert_bf16<<<ALL_CHUNKS / 256, 256, 0, stream>>>(feats, feats_s, T);
    dim3 g1(P_IDS, 4);
    phase1<<<g1, 256, 0, stream>>>(T, pmax, pmin);
    phase2<<<B_DIM / 64, 256, 0, stream>>>(pmax, pmin, labels, out);
}